// Round 2
// baseline (1089.467 us; speedup 1.0000x reference)
//
#include <hip/hip_runtime.h>
#include <math.h>

#define N_TOK 1024
#define D_DIM 768
#define H_N   12
#define DH    64
#define DP    128
#define SCALE 0.125f
#define EPS   1e-5f
#define NN    (N_TOK * N_TOK)

// ---------------------------------------------------------------------------
// prep: W2[c,h] = pair_ln_w[c] * bias_W[c,h]
//       S2[h]   = sum_c W2[c,h]
//       cb[h]   = sum_c pair_ln_b[c] * bias_W[c,h] + bias_b[h]
// so that LN(p) . W_h == (p . W2_h - mean(p)*S2[h]) * rstd + cb[h]
// ---------------------------------------------------------------------------
__global__ __launch_bounds__(128) void prep_kernel(
    const float* __restrict__ pair_ln_w, const float* __restrict__ pair_ln_b,
    const float* __restrict__ bias_W, const float* __restrict__ bias_b,
    float* __restrict__ W2, float* __restrict__ S2cb)
{
    __shared__ float Ws[DP * H_N];
    __shared__ float slw[DP], slb[DP];
    int t = threadIdx.x; // 128 threads
    slw[t] = pair_ln_w[t];
    slb[t] = pair_ln_b[t];
    for (int idx = t; idx < DP * H_N; idx += 128) Ws[idx] = bias_W[idx];
    __syncthreads();
    for (int idx = t; idx < DP * H_N; idx += 128) {
        int c = idx / H_N;
        W2[idx] = slw[c] * Ws[idx];
    }
    if (t < 24) {
        int h = t % H_N;
        bool isS = t < H_N;
        float s = 0.f;
        for (int c = 0; c < DP; ++c)
            s += (isS ? slw[c] : slb[c]) * Ws[c * H_N + h];
        S2cb[t] = isS ? s : (s + bias_b[h]);
    }
}

// ---------------------------------------------------------------------------
// Row LayerNorm over 768 cols. One block (256 thr) per row, 3 elems/thread.
// Works in-place (block owns its whole row).
// ---------------------------------------------------------------------------
__global__ __launch_bounds__(256) void ln_kernel(
    const float* __restrict__ in, float* __restrict__ out,
    int istride, int ostride,
    const float* __restrict__ w, const float* __restrict__ b)
{
    int row = blockIdx.x;
    int tid = threadIdx.x;
    const float* ip = in + (size_t)row * istride;
    float v0 = ip[tid], v1 = ip[tid + 256], v2 = ip[tid + 512];
    float s = v0 + v1 + v2;
    float q = v0 * v0 + v1 * v1 + v2 * v2;
    __shared__ float red[8];
    #pragma unroll
    for (int o = 32; o > 0; o >>= 1) {
        s += __shfl_down(s, o);
        q += __shfl_down(q, o);
    }
    int lane = tid & 63, wv = tid >> 6;
    if (lane == 0) { red[wv] = s; red[4 + wv] = q; }
    __syncthreads();
    if (tid == 0) {
        float ss = red[0] + red[1] + red[2] + red[3];
        float qq = red[4] + red[5] + red[6] + red[7];
        float mean = ss * (1.f / 768.f);
        float var = qq * (1.f / 768.f) - mean * mean;
        red[0] = mean;
        red[1] = rsqrtf(var + EPS);
    }
    __syncthreads();
    float mean = red[0], rstd = red[1];
    float* op = out + (size_t)row * ostride;
    op[tid]       = (v0 - mean) * rstd * w[tid]       + b[tid];
    op[tid + 256] = (v1 - mean) * rstd * w[tid + 256] + b[tid + 256];
    op[tid + 512] = (v2 - mean) * rstd * w[tid + 512] + b[tid + 512];
}

// ---------------------------------------------------------------------------
// Tiled fp32 GEMM: C[M,N] = A[M,K] @ B + bias-row.  BM=BN=64, BK=16, 256 thr,
// 4x4 micro-tile. Column source switches from (B0,bias0) to (B1,bias1) at
// `split` (split % 64 == 0 so whole blocks are uniform).
// ---------------------------------------------------------------------------
__global__ __launch_bounds__(256) void sgemm(
    const float* __restrict__ A, int lda,
    const float* __restrict__ B0, int ldb0, const float* __restrict__ bias0,
    const float* __restrict__ B1, int ldb1, const float* __restrict__ bias1,
    int split, float* __restrict__ C, int ldc, int K)
{
    __shared__ float As[16 * 68];
    __shared__ float Bs[16 * 68];
    int tid = threadIdx.x;
    int tx = tid & 15, ty = tid >> 4;
    int m0 = blockIdx.y * 64, n0 = blockIdx.x * 64;
    const float* Bp; const float* bp; int ldb, bcol0;
    if (n0 < split) { Bp = B0; bp = bias0; ldb = ldb0; bcol0 = n0; }
    else            { Bp = B1; bp = bias1; ldb = ldb1; bcol0 = n0 - split; }

    float acc[4][4] = {};
    int ar = tid >> 2, ak = (tid & 3) * 4;   // A loader: 64 rows x 4 float4(k)
    int bk = tid >> 4, bc = (tid & 15) * 4;  // B loader: 16 k   x 16 float4(n)

    for (int kt = 0; kt < K; kt += 16) {
        float4 av = *(const float4*)&A[(size_t)(m0 + ar) * lda + kt + ak];
        float4 bv = *(const float4*)&Bp[(size_t)(kt + bk) * ldb + bcol0 + bc];
        As[(ak + 0) * 68 + ar] = av.x;
        As[(ak + 1) * 68 + ar] = av.y;
        As[(ak + 2) * 68 + ar] = av.z;
        As[(ak + 3) * 68 + ar] = av.w;
        *(float4*)&Bs[bk * 68 + bc] = bv;
        __syncthreads();
        #pragma unroll
        for (int kk = 0; kk < 16; ++kk) {
            float4 a = *(const float4*)&As[kk * 68 + ty * 4];
            float4 b = *(const float4*)&Bs[kk * 68 + tx * 4];
            acc[0][0] += a.x * b.x; acc[0][1] += a.x * b.y; acc[0][2] += a.x * b.z; acc[0][3] += a.x * b.w;
            acc[1][0] += a.y * b.x; acc[1][1] += a.y * b.y; acc[1][2] += a.y * b.z; acc[1][3] += a.y * b.w;
            acc[2][0] += a.z * b.x; acc[2][1] += a.z * b.y; acc[2][2] += a.z * b.z; acc[2][3] += a.z * b.w;
            acc[3][0] += a.w * b.x; acc[3][1] += a.w * b.y; acc[3][2] += a.w * b.z; acc[3][3] += a.w * b.w;
        }
        __syncthreads();
    }
    float4 bb = *(const float4*)&bp[bcol0 + tx * 4];
    #pragma unroll
    for (int u = 0; u < 4; ++u) {
        float4 o;
        o.x = acc[u][0] + bb.x; o.y = acc[u][1] + bb.y;
        o.z = acc[u][2] + bb.z; o.w = acc[u][3] + bb.w;
        *(float4*)&C[(size_t)(m0 + ty * 4 + u) * ldc + n0 + tx * 4] = o;
    }
}

// ---------------------------------------------------------------------------
// bias[h,i,j] = (p[i,j,:].W2_h - mean*S2_h)*rstd + cb_h + (mask? 0 : -1e4)
// One thread per (i,j); consecutive threads = consecutive j (coalesced writes).
// mask is a JAX bool delivered as int32 (harness "integer -> const int*").
// ---------------------------------------------------------------------------
__global__ __launch_bounds__(256) void bias_kernel(
    const float* __restrict__ pair, const int* __restrict__ mask,
    const float* __restrict__ W2, const float* __restrict__ S2cb,
    float* __restrict__ biasbuf)
{
    __shared__ float sW2[DP * H_N];
    __shared__ float sS[H_N], sC[H_N];
    int tid = threadIdx.x;
    for (int t = tid; t < DP * H_N; t += 256) sW2[t] = W2[t];
    if (tid < H_N) { sS[tid] = S2cb[tid]; sC[tid] = S2cb[H_N + tid]; }
    __syncthreads();

    int gid = blockIdx.x * 256 + tid;           // gid = i*1024 + j
    const float4* p4 = (const float4*)(pair + (size_t)gid * DP);
    float sum = 0.f, ssq = 0.f;
    float dot[H_N];
    #pragma unroll
    for (int h = 0; h < H_N; ++h) dot[h] = 0.f;

    #pragma unroll 4
    for (int c4 = 0; c4 < 32; ++c4) {
        float4 v = p4[c4];
        float e[4] = { v.x, v.y, v.z, v.w };
        #pragma unroll
        for (int k = 0; k < 4; ++k) {
            float x = e[k];
            sum += x; ssq += x * x;
            const float* wp = &sW2[(c4 * 4 + k) * H_N];
            #pragma unroll
            for (int h = 0; h < H_N; ++h) dot[h] += x * wp[h];
        }
    }
    float mean = sum * (1.f / 128.f);
    float var  = ssq * (1.f / 128.f) - mean * mean;
    float rstd = rsqrtf(var + EPS);
    float mz = (mask[gid] != 0) ? 0.f : -10000.f;
    #pragma unroll
    for (int h = 0; h < H_N; ++h)
        biasbuf[(size_t)h * NN + gid] = (dot[h] - mean * sS[h]) * rstd + sC[h] + mz;
}

// ---------------------------------------------------------------------------
// Flash attention per (head, 16-row tile). Bc=32 K/V tiles via LDS, online
// softmax, sigmoid(g) gating fused in epilogue.
// xw layout per row: [ q(768, LN'd) | k(768, LN'd) | v(768) | g(768) ]
// ---------------------------------------------------------------------------
__global__ __launch_bounds__(256) void attn_kernel(
    const float* __restrict__ xw, const float* __restrict__ biasbuf,
    float* __restrict__ attn_out)
{
    const int h  = blockIdx.y;
    const int i0 = blockIdx.x * 16;
    const int tid = threadIdx.x;
    const int tx = tid & 15, ty = tid >> 4;

    __shared__ float Qs[16 * 65];
    __shared__ float Ks[32 * 65];
    __shared__ float Vs[32 * 68];
    __shared__ float Ps[16 * 33];

    {   // stage Q (scale folded)
        int r = tid >> 4, c4 = (tid & 15) * 4;
        float4 v = *(const float4*)(xw + (size_t)(i0 + r) * 3072 + h * 64 + c4);
        float* d = &Qs[r * 65 + c4];
        d[0] = v.x * SCALE; d[1] = v.y * SCALE; d[2] = v.z * SCALE; d[3] = v.w * SCALE;
    }

    float m = -1e30f, l = 0.f;
    float a0 = 0.f, a1 = 0.f, a2 = 0.f, a3 = 0.f;
    const float* brow = biasbuf + (size_t)h * NN + (size_t)(i0 + ty) * N_TOK;

    for (int j0 = 0; j0 < N_TOK; j0 += 32) {
        #pragma unroll
        for (int q2 = 0; q2 < 2; ++q2) {       // stage K, V tiles (32x64)
            int idx = tid + q2 * 256;
            int r = idx >> 4, c4 = (idx & 15) * 4;
            const float* kb = xw + (size_t)(j0 + r) * 3072 + 768 + h * 64 + c4;
            float4 kv = *(const float4*)kb;
            float* kd = &Ks[r * 65 + c4];
            kd[0] = kv.x; kd[1] = kv.y; kd[2] = kv.z; kd[3] = kv.w;
            float4 vv = *(const float4*)(kb + 768);
            *(float4*)&Vs[r * 68 + c4] = vv;
        }
        __syncthreads();

        // S: each thread -> row ty, cols {2tx, 2tx+1}
        float s0 = 0.f, s1 = 0.f;
        const float* qrow = &Qs[ty * 65];
        const float* k0 = &Ks[(2 * tx) * 65];
        const float* k1 = k0 + 65;
        #pragma unroll
        for (int d = 0; d < 64; ++d) {
            float qv = qrow[d];
            s0 += qv * k0[d];
            s1 += qv * k1[d];
        }
        s0 += brow[j0 + 2 * tx];
        s1 += brow[j0 + 2 * tx + 1];

        // online softmax (reduce across the 16 tx lanes of this row)
        float mt = fmaxf(s0, s1);
        #pragma unroll
        for (int o = 1; o < 16; o <<= 1) mt = fmaxf(mt, __shfl_xor(mt, o));
        float mn = fmaxf(m, mt);
        float al = __expf(m - mn);
        float p0 = __expf(s0 - mn);
        float p1 = __expf(s1 - mn);
        float rs = p0 + p1;
        #pragma unroll
        for (int o = 1; o < 16; o <<= 1) rs += __shfl_xor(rs, o);
        l = l * al + rs;
        m = mn;
        a0 *= al; a1 *= al; a2 *= al; a3 *= al;
        Ps[ty * 33 + 2 * tx]     = p0;
        Ps[ty * 33 + 2 * tx + 1] = p1;
        __syncthreads();

        // O: row ty, d-cols {4tx..4tx+3}
        const float* prow = &Ps[ty * 33];
        #pragma unroll
        for (int j = 0; j < 32; ++j) {
            float pv = prow[j];
            float4 vv = *(const float4*)&Vs[j * 68 + tx * 4];
            a0 += pv * vv.x; a1 += pv * vv.y; a2 += pv * vv.z; a3 += pv * vv.w;
        }
        __syncthreads();
    }

    float inv = 1.f / l;
    int row = i0 + ty;
    float4 gv = *(const float4*)(xw + (size_t)row * 3072 + 2304 + h * 64 + tx * 4);
    float* op = attn_out + (size_t)row * 768 + h * 64 + tx * 4;
    op[0] = a0 * inv / (1.f + __expf(-gv.x));
    op[1] = a1 * inv / (1.f + __expf(-gv.y));
    op[2] = a2 * inv / (1.f + __expf(-gv.z));
    op[3] = a3 * inv / (1.f + __expf(-gv.w));
}

// ---------------------------------------------------------------------------
extern "C" void kernel_launch(void* const* d_in, const int* in_sizes, int n_in,
                              void* d_out, int out_size, void* d_ws, size_t ws_size,
                              hipStream_t stream)
{
    const float* node      = (const float*)d_in[0];
    const float* pair      = (const float*)d_in[1];
    const float* ln_node_w = (const float*)d_in[2];
    const float* ln_node_b = (const float*)d_in[3];
    const float* pair_ln_w = (const float*)d_in[4];
    const float* pair_ln_b = (const float*)d_in[5];
    const float* qkv_W     = (const float*)d_in[6];
    const float* qkv_b     = (const float*)d_in[7];
    const float* q_ln_w    = (const float*)d_in[8];
    const float* q_ln_b    = (const float*)d_in[9];
    const float* k_ln_w    = (const float*)d_in[10];
    const float* k_ln_b    = (const float*)d_in[11];
    const float* g_W       = (const float*)d_in[12];
    const float* g_b       = (const float*)d_in[13];
    const float* bias_W    = (const float*)d_in[14];
    const float* bias_b    = (const float*)d_in[15];
    const float* out_W     = (const float*)d_in[16];
    const float* out_b     = (const float*)d_in[17];
    const int*   mask      = (const int*)d_in[18]; // jax bool delivered as int32
    float* out = (float*)d_out;

    float* ws      = (float*)d_ws;
    float* x       = ws;                   // 1024*768
    float* xw      = x + 786432;           // 1024*3072  [q|k|v|g]
    float* W2      = xw + 3145728;         // 128*12
    float* S2cb    = W2 + 1536;            // 24 (padded 32)
    float* biasbuf = S2cb + 32;            // 12*1024*1024
    float* attn_o  = biasbuf + 12582912;   // 1024*768

    prep_kernel<<<1, 128, 0, stream>>>(pair_ln_w, pair_ln_b, bias_W, bias_b, W2, S2cb);
    ln_kernel<<<1024, 256, 0, stream>>>(node, x, 768, 768, ln_node_w, ln_node_b);
    sgemm<<<dim3(48, 16), 256, 0, stream>>>(x, 768,
                                            qkv_W, 2304, qkv_b,
                                            g_W, 768, g_b,
                                            2304, xw, 3072, 768);
    ln_kernel<<<1024, 256, 0, stream>>>(xw, xw, 3072, 3072, q_ln_w, q_ln_b);
    ln_kernel<<<1024, 256, 0, stream>>>(xw + 768, xw + 768, 3072, 3072, k_ln_w, k_ln_b);
    bias_kernel<<<4096, 256, 0, stream>>>(pair, mask, W2, S2cb, biasbuf);
    attn_kernel<<<dim3(64, 12), 256, 0, stream>>>(xw, biasbuf, attn_o);
    sgemm<<<dim3(12, 16), 256, 0, stream>>>(attn_o, 768,
                                            out_W, 768, out_b,
                                            out_W, 768, out_b,
                                            1 << 30, out, 768, 768);
}